// Round 2
// baseline (30420.822 us; speedup 1.0000x reference)
//
#include <hip/hip_runtime.h>

typedef _Float16 half8 __attribute__((ext_vector_type(8)));
typedef _Float16 half4v __attribute__((ext_vector_type(4)));
typedef float f32x4 __attribute__((ext_vector_type(4)));

#define T_LEN 2048
#define BSZ   64
#define INSZ  256
#define HSZ   512
#define G4H   2048

// workspace layout (bytes)
#define OFF_XW   0ULL           // [2048][64][2048] fp16 = 536,870,912
#define OFF_X16  536870912ULL   // [131072][256] fp16   =  67,108,864
#define OFF_WIT  603979776ULL   // [2048][256] fp16     =   1,048,576
#define OFF_WHT  605028352ULL   // [2048][512] fp16     =   2,097,152
#define OFF_HBUF 607125504ULL   // [2][64][512] fp16    =     131,072
#define OFF_CTR  607256576ULL   // flags: 4 groups x 32 words

__device__ __forceinline__ float fast_rcp(float x) { return __builtin_amdgcn_rcpf(x); }
__device__ __forceinline__ float sigm(float x)  { return fast_rcp(1.f + __expf(-x)); }
__device__ __forceinline__ float tanhf_(float x){ return 1.f - 2.f * fast_rcp(1.f + __expf(2.f * x)); }

// ---- explicit-asm memory primitives (loop VMEM is 100% asm: exact vmcnt counts) ----
template<int OFF>
__device__ __forceinline__ half8 ldg_coh_b128(const _Float16* p) {
    half8 r;
    asm volatile("global_load_dwordx4 %0, %1, off offset:%2 sc0 sc1"
                 : "=v"(r) : "v"(p), "n"(OFF));
    return r;
}
template<int OFF>
__device__ __forceinline__ unsigned ldg_u16(const _Float16* p) {
    unsigned r;
    asm volatile("global_load_ushort %0, %1, off offset:%2"
                 : "=v"(r) : "v"(p), "n"(OFF));
    return r;
}
__device__ __forceinline__ unsigned ldg_coh_u32(const unsigned* p) {
    unsigned r;
    asm volatile("global_load_dword %0, %1, off sc0 sc1" : "=v"(r) : "v"(p));
    return r;
}
__device__ __forceinline__ void stg_short_sc(_Float16* p, unsigned v) {
    asm volatile("global_store_short %0, %1, off sc0 sc1" :: "v"(p), "v"(v));
}
__device__ __forceinline__ void stg_dword_nt(float* p, float v) {
    asm volatile("global_store_dword %0, %1, off nt" :: "v"(p), "v"(v));
}
__device__ __forceinline__ void stg_dword_sc(unsigned* p, unsigned v) {
    asm volatile("global_store_dword %0, %1, off sc0 sc1" :: "v"(p), "v"(v));
}

// ---------- phase 0: converts / transposes / init ----------
__global__ void convert_x(const float* __restrict__ x, _Float16* __restrict__ x16, int n4) {
    int i = blockIdx.x * blockDim.x + threadIdx.x;
    int stride = gridDim.x * blockDim.x;
    const float4* xv = (const float4*)x;
    for (; i < n4; i += stride) {
        float4 v = xv[i];
        half4v h;
        h[0] = (_Float16)v.x; h[1] = (_Float16)v.y;
        h[2] = (_Float16)v.z; h[3] = (_Float16)v.w;
        *(half4v*)(x16 + (size_t)i * 4) = h;
    }
}

__global__ void transpose_w(const float* __restrict__ W, _Float16* __restrict__ WT, int K) {
    int id = blockIdx.x * blockDim.x + threadIdx.x;
    int total = K * G4H, stride = gridDim.x * blockDim.x;
    for (; id < total; id += stride) {
        int k = id >> 11;
        int n = id & 2047;
        WT[(size_t)n * K + k] = (_Float16)W[id];
    }
}

__global__ void init_state(unsigned* __restrict__ hbuf_u, unsigned* __restrict__ ctr) {
    int id = blockIdx.x * blockDim.x + threadIdx.x;
    // write-through so zeros are at the coherence point for the scan's sc reads
    if (id < 32768) __hip_atomic_store(hbuf_u + id, 0u, __ATOMIC_RELAXED, __HIP_MEMORY_SCOPE_AGENT);
    if (id < 128)   __hip_atomic_store(ctr + id, 0u, __ATOMIC_RELAXED, __HIP_MEMORY_SCOPE_AGENT);
}

// ---------- phase 1: xW = x16 @ Wi + bias, fp16 out ----------
__global__ __launch_bounds__(256) void gemm_xw(const _Float16* __restrict__ A,
                                               const _Float16* __restrict__ Bt,
                                               const float* __restrict__ bias,
                                               _Float16* __restrict__ C) {
    __shared__ __align__(16) _Float16 As[128 * 32];
    __shared__ __align__(16) _Float16 Bs[128 * 32];
    const int tid  = threadIdx.x;
    const int w    = tid >> 6;
    const int l    = tid & 63;
    const int lo   = l & 15;
    const int quad = l >> 4;
    const int rowBase = blockIdx.y * 128;
    const int colBase = blockIdx.x * 128;
    const int wr = (w >> 1) * 64, wc = (w & 1) * 64;

    f32x4 acc[4][4] = {};

    const int v0 = tid, v1 = tid + 256;
    for (int kt = 0; kt < 8; kt++) {
        ((half8*)As)[v0] = *(const half8*)(A + (size_t)(rowBase + (v0 >> 2)) * INSZ + kt * 32 + (v0 & 3) * 8);
        ((half8*)As)[v1] = *(const half8*)(A + (size_t)(rowBase + (v1 >> 2)) * INSZ + kt * 32 + (v1 & 3) * 8);
        ((half8*)Bs)[v0] = *(const half8*)(Bt + (size_t)(colBase + (v0 >> 2)) * INSZ + kt * 32 + (v0 & 3) * 8);
        ((half8*)Bs)[v1] = *(const half8*)(Bt + (size_t)(colBase + (v1 >> 2)) * INSZ + kt * 32 + (v1 & 3) * 8);
        __syncthreads();
        half8 af[4], bf[4];
#pragma unroll
        for (int mt = 0; mt < 4; mt++)
            af[mt] = *(const half8*)(As + (wr + mt * 16 + lo) * 32 + quad * 8);
#pragma unroll
        for (int nt = 0; nt < 4; nt++)
            bf[nt] = *(const half8*)(Bs + (wc + nt * 16 + lo) * 32 + quad * 8);
#pragma unroll
        for (int mt = 0; mt < 4; mt++)
#pragma unroll
            for (int nt = 0; nt < 4; nt++)
                acc[mt][nt] = __builtin_amdgcn_mfma_f32_16x16x32_f16(af[mt], bf[nt], acc[mt][nt], 0, 0, 0);
        __syncthreads();
    }

#pragma unroll
    for (int nt = 0; nt < 4; nt++) {
        int col = colBase + wc + nt * 16 + lo;
        float bv = bias[col];
#pragma unroll
        for (int mt = 0; mt < 4; mt++) {
#pragma unroll
            for (int r = 0; r < 4; r++) {
                int row = rowBase + wr + mt * 16 + quad * 4 + r;
                C[(size_t)row * G4H + col] = (_Float16)(acc[mt][nt][r] + bv);
            }
        }
    }
}

// ---------- phase 2: persistent recurrent scan, group time-multiplexed ----------
// 8 blocks = 8 col-blocks (64 h-cols each). Each block round-robins all 4
// sample-groups per step (4 "slots"/step). The ~3-slot gap between producing
// a group's h and consuming it hides the MALL sync/load latency:
//   slot s: [confirm peek(regs) | prefetch af'/xq' for slot s+1 | MFMA+epi |
//            peek for slot s+2 | 8 stores | vmcnt(8) | s_barrier |
//            delayed signal for slot s-1's group]
// vmcnt(8) leaves exactly this slot's 8 stores in flight; it drains the
// PREVIOUS slot's stores (oldest, in-order retirement), so the signal after
// the barrier is data-safe with a full slot of extra margin.
__global__ __launch_bounds__(256, 1) void lstm_scan(const _Float16* __restrict__ xw,   // [T][64][2048]
                                                    const _Float16* __restrict__ whT,  // [2048][512]
                                                    _Float16* __restrict__ hbuf,       // [2][64][512]
                                                    unsigned* __restrict__ ctr,        // [4][32] flags
                                                    float* __restrict__ out) {
    __shared__ __align__(16) _Float16 ldsW[2 * 16 * 256 * 8];   // 128 KB
    half8* ldsF = (half8*)ldsW;

    const int tid  = threadIdx.x;
    const int w    = tid >> 6;
    const int l    = tid & 63;
    const int lo   = l & 15;
    const int quad = l >> 4;
    const int j    = blockIdx.x;            // col-block 0..7
    const int col  = j * 64 + w * 16 + lo;  // h column
    const int sr0  = quad * 4;              // C-layout sample-row base within group

    // gates q=2,3 -> LDS (lane-private fragment slots, loaded once)
#pragma unroll
    for (int qq = 0; qq < 2; qq++) {
        const _Float16* wrow = whT + (size_t)((qq + 2) * HSZ + col) * HSZ + quad * 8;
#pragma unroll
        for (int kt = 0; kt < 16; kt++)
            ldsF[(qq * 16 + kt) * 256 + tid] = *(const half8*)(wrow + kt * 32);
    }
    // gates q=0,1 -> registers
    half8 bfrag[2][16];
#pragma unroll
    for (int q = 0; q < 2; q++) {
        const _Float16* wrow = whT + (size_t)(q * HSZ + col) * HSZ + quad * 8;
#pragma unroll
        for (int kt = 0; kt < 16; kt++)
            bfrag[q][kt] = *(const half8*)(wrow + kt * 32);
    }
    __syncthreads();   // drains staging loads; compiler VMEM ledger clean from here

    float creg[4][4]  = {};
    float hlast[4][4] = {};
    half8 afA[16], afB[16];
    unsigned xqA[16], xqB[16];
    unsigned pkA = 0, pkB = 0;
#pragma unroll
    for (int kt = 0; kt < 16; kt++) { half8 z = {}; afA[kt] = z; }   // h(-1) = 0

#define AF_LOAD16(DST, P)                                                   \
    DST[0]  = ldg_coh_b128<0>(P);   DST[1]  = ldg_coh_b128<64>(P);          \
    DST[2]  = ldg_coh_b128<128>(P); DST[3]  = ldg_coh_b128<192>(P);         \
    DST[4]  = ldg_coh_b128<256>(P); DST[5]  = ldg_coh_b128<320>(P);         \
    DST[6]  = ldg_coh_b128<384>(P); DST[7]  = ldg_coh_b128<448>(P);         \
    DST[8]  = ldg_coh_b128<512>(P); DST[9]  = ldg_coh_b128<576>(P);         \
    DST[10] = ldg_coh_b128<640>(P); DST[11] = ldg_coh_b128<704>(P);         \
    DST[12] = ldg_coh_b128<768>(P); DST[13] = ldg_coh_b128<832>(P);         \
    DST[14] = ldg_coh_b128<896>(P); DST[15] = ldg_coh_b128<960>(P);

#define XQ_LOAD(DST, XB)                                                    \
    { const _Float16 *x0_ = (XB), *x1_ = (XB) + G4H,                        \
                     *x2_ = (XB) + 2 * G4H, *x3_ = (XB) + 3 * G4H;          \
      DST[0]  = ldg_u16<0>(x0_);    DST[4]  = ldg_u16<1024>(x0_);           \
      DST[8]  = ldg_u16<2048>(x0_); DST[12] = ldg_u16<3072>(x0_);           \
      DST[1]  = ldg_u16<0>(x1_);    DST[5]  = ldg_u16<1024>(x1_);           \
      DST[9]  = ldg_u16<2048>(x1_); DST[13] = ldg_u16<3072>(x1_);           \
      DST[2]  = ldg_u16<0>(x2_);    DST[6]  = ldg_u16<1024>(x2_);           \
      DST[10] = ldg_u16<2048>(x2_); DST[14] = ldg_u16<3072>(x2_);           \
      DST[3]  = ldg_u16<0>(x3_);    DST[7]  = ldg_u16<1024>(x3_);           \
      DST[11] = ldg_u16<2048>(x3_); DST[15] = ldg_u16<3072>(x3_); }

    { // prologue: xW prefetch for slot (t=0, g=0)
        const _Float16* xb0 = xw + (size_t)sr0 * G4H + col;
        XQ_LOAD(xqA, xb0)
        asm volatile("s_waitcnt vmcnt(0)");
        __builtin_amdgcn_sched_barrier(0);
    }

#define SLOT(G, AFU, AFL, XQU, XQL, PKU, PKL)                               \
{                                                                           \
    constexpr int g_ = (G);                                                 \
    const int gn_ = (g_ + 1) & 3;                                           \
    const int tn_ = (g_ == 3) ? t + 1 : t;                                  \
    /* confirm peers done writing h[gn_](tn_-1) before prefetching it */    \
    if (tn_ > 0 && tn_ < T_LEN) {                                           \
        const unsigned need_ = (unsigned)tn_;                               \
        const unsigned* pa_ = ctr + gn_ * 32 + (l & 7);                     \
        while (!__all((int)(PKU >= need_))) {                               \
            PKU = ldg_coh_u32(pa_);                                         \
            asm volatile("s_waitcnt vmcnt(0)");                             \
            __builtin_amdgcn_sched_barrier(0);                              \
        }                                                                   \
    }                                                                       \
    /* prefetch next slot's A-fragments + xW (hidden behind this MFMA) */   \
    if (tn_ < T_LEN) {                                                      \
        const _Float16* hr_ = hbuf + (size_t)((tn_ - 1) & 1) * (BSZ * HSZ)  \
                              + (size_t)(gn_ * 16 + lo) * HSZ + quad * 8;   \
        AF_LOAD16(AFL, hr_)                                                 \
        const _Float16* xb_ = xw + ((size_t)tn_ * BSZ + gn_ * 16 + sr0) * G4H + col; \
        XQ_LOAD(XQL, xb_)                                                   \
    }                                                                       \
    /* compute gates for (t, g_) — AFU/XQU were drained last slot */        \
    f32x4 acc[4];                                                           \
    _Pragma("unroll")                                                       \
    for (int q_ = 0; q_ < 4; q_++) {                                        \
        _Pragma("unroll")                                                   \
        for (int r_ = 0; r_ < 4; r_++)                                      \
            acc[q_][r_] = (float)__builtin_bit_cast(_Float16, (unsigned short)XQU[q_ * 4 + r_]); \
    }                                                                       \
    _Pragma("unroll")                                                       \
    for (int kt_ = 0; kt_ < 16; kt_++) {                                    \
        acc[0] = __builtin_amdgcn_mfma_f32_16x16x32_f16(AFU[kt_], bfrag[0][kt_], acc[0], 0, 0, 0); \
        acc[1] = __builtin_amdgcn_mfma_f32_16x16x32_f16(AFU[kt_], bfrag[1][kt_], acc[1], 0, 0, 0); \
        half8 b2_ = ldsF[kt_ * 256 + tid];                                  \
        half8 b3_ = ldsF[(16 + kt_) * 256 + tid];                           \
        acc[2] = __builtin_amdgcn_mfma_f32_16x16x32_f16(AFU[kt_], b2_, acc[2], 0, 0, 0); \
        acc[3] = __builtin_amdgcn_mfma_f32_16x16x32_f16(AFU[kt_], b3_, acc[3], 0, 0, 0); \
    }                                                                       \
    /* peek flags for the slot after next (consumed at next slot's confirm) */ \
    if (((g_ >= 2) ? t + 1 : t) < T_LEN)                                    \
        PKL = ldg_coh_u32(ctr + ((g_ + 2) & 3) * 32 + (l & 7));             \
    /* epilogue + stores (8 asm stores = the youngest VMEM of this slot) */ \
    _Pragma("unroll")                                                       \
    for (int r_ = 0; r_ < 4; r_++) {                                        \
        float iv = sigm(acc[0][r_]);                                        \
        float fv = sigm(acc[1][r_]);                                        \
        float gv = tanhf_(acc[2][r_]);                                      \
        float ov = sigm(acc[3][r_]);                                        \
        float cn = fv * creg[g_][r_] + iv * gv;                             \
        creg[g_][r_] = cn;                                                  \
        float hn = ov * tanhf_(cn);                                         \
        hlast[g_][r_] = hn;                                                 \
        const size_t brow_ = (size_t)(g_ * 16 + sr0 + r_);                  \
        stg_short_sc(hbuf + (size_t)(t & 1) * (BSZ * HSZ) + brow_ * HSZ + col, \
                     (unsigned)__builtin_bit_cast(unsigned short, (_Float16)hn)); \
        stg_dword_nt(out + ((size_t)t * BSZ + brow_) * HSZ + col, hn);      \
    }                                                                       \
    /* drain all loads + PREVIOUS slot's stores; leave this slot's 8 stores */ \
    asm volatile("s_waitcnt vmcnt(8)");                                     \
    __builtin_amdgcn_sched_barrier(0);                                      \
    __builtin_amdgcn_s_barrier();                                           \
    /* delayed signal: previous slot's h is drained block-wide + 1 slot margin */ \
    if (!(t == 0 && g_ == 0) && tid == 0) {                                 \
        stg_dword_sc(ctr + ((g_ + 3) & 3) * 32 + j,                         \
                     (unsigned)(((g_ == 0) ? t - 1 : t) + 1));              \
    }                                                                       \
}

    for (int t = 0; t < T_LEN; t++) {
        SLOT(0, afA, afB, xqA, xqB, pkA, pkB)
        SLOT(1, afB, afA, xqB, xqA, pkB, pkA)
        SLOT(2, afA, afB, xqA, xqB, pkA, pkB)
        SLOT(3, afB, afA, xqB, xqA, pkB, pkA)
    }

#undef SLOT
#undef AF_LOAD16
#undef XQ_LOAD

    // final hT / cT from registers (plain stores; end-of-kernel flush)
#pragma unroll
    for (int g = 0; g < 4; g++) {
#pragma unroll
        for (int r = 0; r < 4; r++) {
            const size_t brow = (size_t)(g * 16 + sr0 + r);
            out[(size_t)T_LEN * BSZ * HSZ + brow * HSZ + col] = hlast[g][r];
            out[(size_t)T_LEN * BSZ * HSZ + (size_t)BSZ * HSZ + brow * HSZ + col] = creg[g][r];
        }
    }
}

extern "C" void kernel_launch(void* const* d_in, const int* in_sizes, int n_in,
                              void* d_out, int out_size, void* d_ws, size_t ws_size,
                              hipStream_t stream) {
    const float* x  = (const float*)d_in[0];   // [2048,64,256]
    const float* Wi = (const float*)d_in[1];   // [256,2048]
    const float* Wh = (const float*)d_in[2];   // [512,2048]
    const float* B  = (const float*)d_in[3];   // [2048]
    float* out = (float*)d_out;

    char* ws = (char*)d_ws;
    _Float16* xW   = (_Float16*)(ws + OFF_XW);
    _Float16* x16  = (_Float16*)(ws + OFF_X16);
    _Float16* WiT  = (_Float16*)(ws + OFF_WIT);
    _Float16* WhT  = (_Float16*)(ws + OFF_WHT);
    _Float16* hbuf = (_Float16*)(ws + OFF_HBUF);
    unsigned* ctr  = (unsigned*)(ws + OFF_CTR);

    hipLaunchKernelGGL(convert_x, dim3(4096), dim3(256), 0, stream, x, x16, 8388608);
    hipLaunchKernelGGL(transpose_w, dim3(512), dim3(256), 0, stream, Wi, WiT, INSZ);
    hipLaunchKernelGGL(transpose_w, dim3(1024), dim3(256), 0, stream, Wh, WhT, HSZ);
    hipLaunchKernelGGL(init_state, dim3(128), dim3(256), 0, stream, (unsigned*)hbuf, ctr);
    hipLaunchKernelGGL(gemm_xw, dim3(16, 1024), dim3(256), 0, stream, x16, WiT, B, xW);
    hipLaunchKernelGGL(lstm_scan, dim3(8), dim3(256), 0, stream, xW, WhT, hbuf, ctr, out);
}

// Round 3
// 11480.384 us; speedup vs baseline: 2.6498x; 2.6498x over previous
//
#include <hip/hip_runtime.h>

typedef _Float16 half8 __attribute__((ext_vector_type(8)));
typedef _Float16 half4v __attribute__((ext_vector_type(4)));
typedef float f32x4 __attribute__((ext_vector_type(4)));

#define T_LEN 2048
#define BSZ   64
#define INSZ  256
#define HSZ   512
#define G4H   2048

// workspace layout (bytes)
#define OFF_XW   0ULL           // [2048][64][2048] fp16 = 536,870,912
#define OFF_X16  536870912ULL   // [131072][256] fp16   =  67,108,864
#define OFF_WIT  603979776ULL   // [2048][256] fp16     =   1,048,576
#define OFF_WHT  605028352ULL   // [2048][512] fp16     =   2,097,152
#define OFF_HBUF 607125504ULL   // [2][64][512] fp16    =     131,072
#define OFF_CTR  607256576ULL   // flags: 4 groups x 32 waves

__device__ __forceinline__ float fast_rcp(float x) { return __builtin_amdgcn_rcpf(x); }
__device__ __forceinline__ float sigm(float x)  { return fast_rcp(1.f + __expf(-x)); }
__device__ __forceinline__ float tanhf_(float x){ return 1.f - 2.f * fast_rcp(1.f + __expf(2.f * x)); }

// ---- explicit-asm memory primitives (ALL loop VMEM is asm: exact vmcnt counts) ----
template<int OFF>
__device__ __forceinline__ half8 ldg_coh_b128(const _Float16* p) {
    half8 r;
    asm volatile("global_load_dwordx4 %0, %1, off offset:%2 sc0 sc1"
                 : "=v"(r) : "v"(p), "n"(OFF));
    return r;
}
template<int OFF>
__device__ __forceinline__ unsigned ldg_u16(const _Float16* p) {
    unsigned r;
    asm volatile("global_load_ushort %0, %1, off offset:%2"
                 : "=v"(r) : "v"(p), "n"(OFF));
    return r;
}
__device__ __forceinline__ unsigned ldg_coh_u32(const unsigned* p) {
    unsigned r;
    asm volatile("global_load_dword %0, %1, off sc0 sc1" : "=v"(r) : "v"(p));
    return r;
}
__device__ __forceinline__ void stg_short_sc(_Float16* p, unsigned v) {
    asm volatile("global_store_short %0, %1, off sc0 sc1" :: "v"(p), "v"(v));
}
__device__ __forceinline__ void stg_dword_nt(float* p, float v) {
    asm volatile("global_store_dword %0, %1, off nt" :: "v"(p), "v"(v));
}
__device__ __forceinline__ void stg_dword_sc(unsigned* p, unsigned v) {
    asm volatile("global_store_dword %0, %1, off sc0 sc1" :: "v"(p), "v"(v));
}

// ---------- phase 0: converts / transposes / init ----------
__global__ void convert_x(const float* __restrict__ x, _Float16* __restrict__ x16, int n4) {
    int i = blockIdx.x * blockDim.x + threadIdx.x;
    int stride = gridDim.x * blockDim.x;
    const float4* xv = (const float4*)x;
    for (; i < n4; i += stride) {
        float4 v = xv[i];
        half4v h;
        h[0] = (_Float16)v.x; h[1] = (_Float16)v.y;
        h[2] = (_Float16)v.z; h[3] = (_Float16)v.w;
        *(half4v*)(x16 + (size_t)i * 4) = h;
    }
}

__global__ void transpose_w(const float* __restrict__ W, _Float16* __restrict__ WT, int K) {
    int id = blockIdx.x * blockDim.x + threadIdx.x;
    int total = K * G4H, stride = gridDim.x * blockDim.x;
    for (; id < total; id += stride) {
        int k = id >> 11;
        int n = id & 2047;
        WT[(size_t)n * K + k] = (_Float16)W[id];
    }
}

__global__ void init_state(unsigned* __restrict__ hbuf_u, unsigned* __restrict__ ctr) {
    int id = blockIdx.x * blockDim.x + threadIdx.x;
    // write-through so zeros are at the coherence point for the scan's sc reads
    if (id < 32768) __hip_atomic_store(hbuf_u + id, 0u, __ATOMIC_RELAXED, __HIP_MEMORY_SCOPE_AGENT);
    if (id < 128)   __hip_atomic_store(ctr + id, 0u, __ATOMIC_RELAXED, __HIP_MEMORY_SCOPE_AGENT);
}

// ---------- phase 1: xW = x16 @ Wi + bias, fp16 out ----------
__global__ __launch_bounds__(256) void gemm_xw(const _Float16* __restrict__ A,
                                               const _Float16* __restrict__ Bt,
                                               const float* __restrict__ bias,
                                               _Float16* __restrict__ C) {
    __shared__ __align__(16) _Float16 As[128 * 32];
    __shared__ __align__(16) _Float16 Bs[128 * 32];
    const int tid  = threadIdx.x;
    const int w    = tid >> 6;
    const int l    = tid & 63;
    const int lo   = l & 15;
    const int quad = l >> 4;
    const int rowBase = blockIdx.y * 128;
    const int colBase = blockIdx.x * 128;
    const int wr = (w >> 1) * 64, wc = (w & 1) * 64;

    f32x4 acc[4][4] = {};

    const int v0 = tid, v1 = tid + 256;
    for (int kt = 0; kt < 8; kt++) {
        ((half8*)As)[v0] = *(const half8*)(A + (size_t)(rowBase + (v0 >> 2)) * INSZ + kt * 32 + (v0 & 3) * 8);
        ((half8*)As)[v1] = *(const half8*)(A + (size_t)(rowBase + (v1 >> 2)) * INSZ + kt * 32 + (v1 & 3) * 8);
        ((half8*)Bs)[v0] = *(const half8*)(Bt + (size_t)(colBase + (v0 >> 2)) * INSZ + kt * 32 + (v0 & 3) * 8);
        ((half8*)Bs)[v1] = *(const half8*)(Bt + (size_t)(colBase + (v1 >> 2)) * INSZ + kt * 32 + (v1 & 3) * 8);
        __syncthreads();
        half8 af[4], bf[4];
#pragma unroll
        for (int mt = 0; mt < 4; mt++)
            af[mt] = *(const half8*)(As + (wr + mt * 16 + lo) * 32 + quad * 8);
#pragma unroll
        for (int nt = 0; nt < 4; nt++)
            bf[nt] = *(const half8*)(Bs + (wc + nt * 16 + lo) * 32 + quad * 8);
#pragma unroll
        for (int mt = 0; mt < 4; mt++)
#pragma unroll
            for (int nt = 0; nt < 4; nt++)
                acc[mt][nt] = __builtin_amdgcn_mfma_f32_16x16x32_f16(af[mt], bf[nt], acc[mt][nt], 0, 0, 0);
        __syncthreads();
    }

#pragma unroll
    for (int nt = 0; nt < 4; nt++) {
        int col = colBase + wc + nt * 16 + lo;
        float bv = bias[col];
#pragma unroll
        for (int mt = 0; mt < 4; mt++) {
#pragma unroll
            for (int r = 0; r < 4; r++) {
                int row = rowBase + wr + mt * 16 + quad * 4 + r;
                C[(size_t)row * G4H + col] = (_Float16)(acc[mt][nt][r] + bv);
            }
        }
    }
}

// ---------- phase 2: persistent recurrent scan, wave-autonomous sync ----------
// 32 blocks = 4 groups (16 samples each) x 8 col-blocks. The 4 groups are
// fully independent recurrences. Within a group, every consumer wave reads
// ALL 32 producer waves' h slices, so sync is per-wave flags:
//   producer wave (g,j,w): 4 h-stores (sc0 sc1, write-through to MALL)
//     -> s_waitcnt vmcnt(0) -> flag store ctr[g*32+j*4+w] = t+1
//   consumer wave: lane l polls ctr[g*32+(l&31)], __all(flag >= t) -> h loads
// No __syncthreads, no RMW chain, no cache maintenance in the loop.
// Fast path: the flag peek is issued at the END of the previous step; exactly
// 20 younger VMEM ops follow it (4 out-stores + 16 xW loads, all asm), so
// `s_waitcnt vmcnt(20)` retires the peek with zero extra latency.
// RAW: flag=t+1 implies that wave's h(t) stores are MALL-visible.
// WAR: flag=t+1 also implies that wave's step-t h loads retired (vmcnt(0)
// drains loads too), so overwriting buffer t&1 at step t+1 is safe.
__global__ __launch_bounds__(256, 1) void lstm_scan(const _Float16* __restrict__ xw,   // [T][64][2048]
                                                    const _Float16* __restrict__ whT,  // [2048][512]
                                                    _Float16* __restrict__ hbuf,       // [2][64][512]
                                                    unsigned* __restrict__ ctr,        // [4][32] flags
                                                    float* __restrict__ out) {
    __shared__ __align__(16) _Float16 ldsW[2 * 16 * 256 * 8];   // 128 KB
    half8* ldsF = (half8*)ldsW;

    const int tid  = threadIdx.x;
    const int w    = tid >> 6;
    const int l    = tid & 63;
    const int lo   = l & 15;
    const int quad = l >> 4;
    const int g    = blockIdx.x & 3;
    const int j    = blockIdx.x >> 2;
    const int col  = j * 64 + w * 16 + lo;  // h column
    const int sr0  = quad * 4;              // C-layout sample-row base
    const int bglob = g * 16;               // first sample of group

    // gates q=2,3 -> LDS (lane-private fragment slots, loaded once)
#pragma unroll
    for (int qq = 0; qq < 2; qq++) {
        const _Float16* wrow = whT + (size_t)((qq + 2) * HSZ + col) * HSZ + quad * 8;
#pragma unroll
        for (int kt = 0; kt < 16; kt++)
            ldsF[(qq * 16 + kt) * 256 + tid] = *(const half8*)(wrow + kt * 32);
    }
    // gates q=0,1 -> registers
    half8 bfrag[2][16];
#pragma unroll
    for (int q = 0; q < 2; q++) {
        const _Float16* wrow = whT + (size_t)(q * HSZ + col) * HSZ + quad * 8;
#pragma unroll
        for (int kt = 0; kt < 16; kt++)
            bfrag[q][kt] = *(const half8*)(wrow + kt * 32);
    }
    __syncthreads();   // drains staging; aligns waves once at loop entry

    float creg[4] = {0.f, 0.f, 0.f, 0.f};
    half8 af[16];
    unsigned xq[16];
    unsigned pk = 0;
    const unsigned* pa = ctr + g * 32 + (l & 31);

#define AF_LOAD16(DST, P)                                                   \
    DST[0]  = ldg_coh_b128<0>(P);   DST[1]  = ldg_coh_b128<64>(P);          \
    DST[2]  = ldg_coh_b128<128>(P); DST[3]  = ldg_coh_b128<192>(P);         \
    DST[4]  = ldg_coh_b128<256>(P); DST[5]  = ldg_coh_b128<320>(P);         \
    DST[6]  = ldg_coh_b128<384>(P); DST[7]  = ldg_coh_b128<448>(P);         \
    DST[8]  = ldg_coh_b128<512>(P); DST[9]  = ldg_coh_b128<576>(P);         \
    DST[10] = ldg_coh_b128<640>(P); DST[11] = ldg_coh_b128<704>(P);         \
    DST[12] = ldg_coh_b128<768>(P); DST[13] = ldg_coh_b128<832>(P);         \
    DST[14] = ldg_coh_b128<896>(P); DST[15] = ldg_coh_b128<960>(P);

#define XQ_LOAD(DST, XB)                                                    \
    { const _Float16 *x0_ = (XB), *x1_ = (XB) + G4H,                        \
                     *x2_ = (XB) + 2 * G4H, *x3_ = (XB) + 3 * G4H;          \
      DST[0]  = ldg_u16<0>(x0_);    DST[4]  = ldg_u16<1024>(x0_);           \
      DST[8]  = ldg_u16<2048>(x0_); DST[12] = ldg_u16<3072>(x0_);           \
      DST[1]  = ldg_u16<0>(x1_);    DST[5]  = ldg_u16<1024>(x1_);           \
      DST[9]  = ldg_u16<2048>(x1_); DST[13] = ldg_u16<3072>(x1_);           \
      DST[2]  = ldg_u16<0>(x2_);    DST[6]  = ldg_u16<1024>(x2_);           \
      DST[10] = ldg_u16<2048>(x2_); DST[14] = ldg_u16<3072>(x2_);           \
      DST[3]  = ldg_u16<0>(x3_);    DST[7]  = ldg_u16<1024>(x3_);           \
      DST[11] = ldg_u16<2048>(x3_); DST[15] = ldg_u16<3072>(x3_); }

    { // prologue: xW for t=0
        const _Float16* xb0 = xw + (size_t)(bglob + sr0) * G4H + col;
        XQ_LOAD(xq, xb0)
        asm volatile("s_waitcnt vmcnt(0)");
        __builtin_amdgcn_sched_barrier(0);
    }

    for (int t = 0; t < T_LEN; t++) {
        const int rb = t & 1, wb = rb ^ 1;

        if (t > 0) {
            // fast path: retire the peek (20 younger asm ops: 4 out + 16 xq)
            asm volatile("s_waitcnt vmcnt(20)");
            __builtin_amdgcn_sched_barrier(0);
            while (!__all((int)(pk >= (unsigned)t))) {
                pk = ldg_coh_u32(pa);
                asm volatile("s_waitcnt vmcnt(0)");
                __builtin_amdgcn_sched_barrier(0);
            }
        }

        // A fragments: h_prev, 16 coherence-point dwordx4 loads
        const _Float16* hrow = hbuf + (size_t)rb * (BSZ * HSZ)
                               + (size_t)(bglob + lo) * HSZ + quad * 8;
        AF_LOAD16(af, hrow)
        asm volatile("s_waitcnt vmcnt(0)");
        __builtin_amdgcn_sched_barrier(0);

        f32x4 acc[4];
#pragma unroll
        for (int q = 0; q < 4; q++)
#pragma unroll
            for (int r = 0; r < 4; r++)
                acc[q][r] = (float)__builtin_bit_cast(_Float16, (unsigned short)xq[q * 4 + r]);

#pragma unroll
        for (int kt = 0; kt < 16; kt++) {
            acc[0] = __builtin_amdgcn_mfma_f32_16x16x32_f16(af[kt], bfrag[0][kt], acc[0], 0, 0, 0);
            acc[1] = __builtin_amdgcn_mfma_f32_16x16x32_f16(af[kt], bfrag[1][kt], acc[1], 0, 0, 0);
            half8 b2 = ldsF[kt * 256 + tid];
            half8 b3 = ldsF[(16 + kt) * 256 + tid];
            acc[2] = __builtin_amdgcn_mfma_f32_16x16x32_f16(af[kt], b2, acc[2], 0, 0, 0);
            acc[3] = __builtin_amdgcn_mfma_f32_16x16x32_f16(af[kt], b3, acc[3], 0, 0, 0);
        }

        // epilogue: gates -> c,h; only the 4 coherent h-stores before the drain
        float hnv[4];
#pragma unroll
        for (int r = 0; r < 4; r++) {
            float iv = sigm(acc[0][r]);
            float fv = sigm(acc[1][r]);
            float gv = tanhf_(acc[2][r]);
            float ov = sigm(acc[3][r]);
            float cn = fv * creg[r] + iv * gv;
            creg[r] = cn;
            float hn = ov * tanhf_(cn);
            hnv[r] = hn;
            const size_t brow = (size_t)(bglob + sr0 + r);
            stg_short_sc(hbuf + (size_t)wb * (BSZ * HSZ) + brow * HSZ + col,
                         (unsigned)__builtin_bit_cast(unsigned short, (_Float16)hn));
        }

        // release: drain h-stores (MALL ack), then publish this wave's flag
        asm volatile("s_waitcnt vmcnt(0)");
        __builtin_amdgcn_sched_barrier(0);
        if (l == 0)
            stg_dword_sc(ctr + g * 32 + j * 4 + w, (unsigned)(t + 1));

        // peek for next step's poll (oldest of the trailing 21 ops)
        pk = ldg_coh_u32(pa);

        // out stores + next xW prefetch overlap the peers' flag latency
#pragma unroll
        for (int r = 0; r < 4; r++) {
            const size_t brow = (size_t)(bglob + sr0 + r);
            stg_dword_nt(out + ((size_t)t * BSZ + brow) * HSZ + col, hnv[r]);
        }
        if (t == T_LEN - 1) {   // final hT/cT (plain stores; end-of-kernel flush)
#pragma unroll
            for (int r = 0; r < 4; r++) {
                const size_t brow = (size_t)(bglob + sr0 + r);
                out[(size_t)T_LEN * BSZ * HSZ + brow * HSZ + col] = hnv[r];
                out[(size_t)T_LEN * BSZ * HSZ + (size_t)BSZ * HSZ + brow * HSZ + col] = creg[r];
            }
        }
        if (t + 1 < T_LEN) {
            const _Float16* xb = xw + ((size_t)(t + 1) * BSZ + bglob + sr0) * G4H + col;
            XQ_LOAD(xq, xb)
        }
    }

#undef AF_LOAD16
#undef XQ_LOAD
}

extern "C" void kernel_launch(void* const* d_in, const int* in_sizes, int n_in,
                              void* d_out, int out_size, void* d_ws, size_t ws_size,
                              hipStream_t stream) {
    const float* x  = (const float*)d_in[0];   // [2048,64,256]
    const float* Wi = (const float*)d_in[1];   // [256,2048]
    const float* Wh = (const float*)d_in[2];   // [512,2048]
    const float* B  = (const float*)d_in[3];   // [2048]
    float* out = (float*)d_out;

    char* ws = (char*)d_ws;
    _Float16* xW   = (_Float16*)(ws + OFF_XW);
    _Float16* x16  = (_Float16*)(ws + OFF_X16);
    _Float16* WiT  = (_Float16*)(ws + OFF_WIT);
    _Float16* WhT  = (_Float16*)(ws + OFF_WHT);
    _Float16* hbuf = (_Float16*)(ws + OFF_HBUF);
    unsigned* ctr  = (unsigned*)(ws + OFF_CTR);

    hipLaunchKernelGGL(convert_x, dim3(4096), dim3(256), 0, stream, x, x16, 8388608);
    hipLaunchKernelGGL(transpose_w, dim3(512), dim3(256), 0, stream, Wi, WiT, INSZ);
    hipLaunchKernelGGL(transpose_w, dim3(1024), dim3(256), 0, stream, Wh, WhT, HSZ);
    hipLaunchKernelGGL(init_state, dim3(128), dim3(256), 0, stream, (unsigned*)hbuf, ctr);
    hipLaunchKernelGGL(gemm_xw, dim3(16, 1024), dim3(256), 0, stream, x16, WiT, B, xW);
    hipLaunchKernelGGL(lstm_scan, dim3(32), dim3(256), 0, stream, xW, WhT, hbuf, ctr, out);
}